// Round 2
// baseline (257.817 us; speedup 1.0000x reference)
//
#include <hip/hip_runtime.h>
#include <stdint.h>

// Problem constants (from reference): B=2, T=2048, D_MODEL=1024, H=16, Dh=64
#define TB 2
#define TT 2048
#define DM 1024
#define NH 16
#define DH 64

typedef __bf16 bf16x8 __attribute__((ext_vector_type(8)));
typedef float f32x4 __attribute__((ext_vector_type(4)));

#define LOG2E 1.4426950408889634f

__device__ __forceinline__ ushort f2bf(float f) {
  uint32_t u = __builtin_bit_cast(uint32_t, f);
  u += 0x7FFFu + ((u >> 16) & 1u);
  return (ushort)(u >> 16);
}

__device__ __forceinline__ void gload_lds16(const void* g, void* l) {
  __builtin_amdgcn_global_load_lds(
      (__attribute__((address_space(1))) void*)g,
      (__attribute__((address_space(3))) void*)l, 16, 0, 0);
}

// ---------------- cast x fp32 -> bf16 (vectorized x4) ----------------
__global__ void cast4_kernel(const float* __restrict__ in, ushort* __restrict__ out, int n4) {
  int i = blockIdx.x * blockDim.x + threadIdx.x;
  if (i < n4) {
    float4 v = ((const float4*)in)[i];
    ushort4 o;
    o.x = f2bf(v.x); o.y = f2bf(v.y); o.z = f2bf(v.z); o.w = f2bf(v.w);
    ((ushort4*)out)[i] = o;
  }
}

// ---------------- transpose + cast: w[K][N] fp32 -> wt[N][K] bf16 ----------------
__global__ void transpose_cast_kernel(const float* __restrict__ w, ushort* __restrict__ wt,
                                      int K, int N) {
  __shared__ float tile[32][33];
  int n0 = blockIdx.x * 32, k0 = blockIdx.y * 32;
  int tx = threadIdx.x, ty = threadIdx.y;  // (32, 8)
#pragma unroll
  for (int i = 0; i < 4; ++i)
    tile[ty + i * 8][tx] = w[(size_t)(k0 + ty + i * 8) * N + n0 + tx];
  __syncthreads();
#pragma unroll
  for (int i = 0; i < 4; ++i)
    wt[(size_t)(n0 + ty + i * 8) * K + k0 + tx] = f2bf(tile[tx][ty + i * 8]);
}

// ---------------- GEMM: C = A[M,K] @ Bt[N,K]^T, bf16 in / fp32 accum ----------------
// 128x128 tile, BK=32, 4 waves each 64x64 (4x4 frags of 16x16x32).
// EPI 0: fp32 out [M,N].  EPI 1: QKV scatter (Q,K -> [b,h,t,d] bf16; V -> [b,h,d,t] bf16).
template <int EPI>
__launch_bounds__(256)
__global__ void gemm_bt_kernel(const ushort* __restrict__ A, const ushort* __restrict__ Bt,
                               float* __restrict__ outF, ushort* __restrict__ Qo,
                               ushort* __restrict__ Ko, ushort* __restrict__ Vto,
                               int M, int N, int K) {
  __shared__ ushort As[128 * 32];
  __shared__ ushort Bs[128 * 32];
  const int tid = threadIdx.x;
  const int lane = tid & 63;
  const int w = tid >> 6;
  const int nb = N >> 7;
  const int bx = blockIdx.x % nb, by = blockIdx.x / nb;
  const int m0 = by << 7, n0 = bx << 7;
  const int wr = (w >> 1) << 6, wc = (w & 1) << 6;
  const int g = lane >> 4, r16 = lane & 15;

  f32x4 acc[4][4] = {};

  const char* Ab = (const char*)A;
  const char* Bb = (const char*)Bt;
  char* AsB = (char*)As;
  char* BsB = (char*)Bs;

  for (int k0 = 0; k0 < K; k0 += 32) {
#pragma unroll
    for (int i = 0; i < 2; ++i) {
      int o = (w << 11) + (i << 10) + (lane << 4);
      int row = o >> 6;
      int ch = (o >> 4) & 3;
      int chl = ch ^ ((row >> 1) & 3);  // logical chunk (inverse-swizzled source)
      gload_lds16(Ab + (size_t)((m0 + row) * K + k0) * 2 + (chl << 4), AsB + o);
      gload_lds16(Bb + (size_t)((n0 + row) * K + k0) * 2 + (chl << 4), BsB + o);
    }
    __syncthreads();

    bf16x8 af[4], bfr[4];
#pragma unroll
    for (int m = 0; m < 4; ++m) {
      int rowA = wr + (m << 4) + r16;
      af[m] = *(const bf16x8*)(AsB + rowA * 64 + ((g ^ ((rowA >> 1) & 3)) << 4));
      int rowB = wc + (m << 4) + r16;
      bfr[m] = *(const bf16x8*)(BsB + rowB * 64 + ((g ^ ((rowB >> 1) & 3)) << 4));
    }
#pragma unroll
    for (int m = 0; m < 4; ++m)
#pragma unroll
      for (int n = 0; n < 4; ++n)
        acc[m][n] = __builtin_amdgcn_mfma_f32_16x16x32_bf16(af[m], bfr[n], acc[m][n], 0, 0, 0);
    __syncthreads();
  }

  if (EPI == 0) {
#pragma unroll
    for (int m = 0; m < 4; ++m)
#pragma unroll
      for (int n = 0; n < 4; ++n)
#pragma unroll
        for (int r = 0; r < 4; ++r) {
          int row = m0 + wr + (m << 4) + (g << 2) + r;
          int col = n0 + wc + (n << 4) + r16;
          outF[(size_t)row * N + col] = acc[m][n][r];
        }
  } else {
    const int colBase = n0 + wc;
#pragma unroll
    for (int m = 0; m < 4; ++m) {
      int trow = m0 + wr + (m << 4) + (g << 2);  // t base for r=0 (b uniform per block)
      int b = trow >> 11;
      int tt = trow & (TT - 1);
#pragma unroll
      for (int n = 0; n < 4; ++n) {
        int e = colBase + (n << 4) + r16;
        int part = e >> 10;
        int rem = e & 1023;
        int h = rem >> 6, d = rem & 63;
        int bh = b * NH + h;
        if (part == 2) {
          ushort p0 = f2bf(acc[m][n][0]), p1 = f2bf(acc[m][n][1]);
          ushort p2 = f2bf(acc[m][n][2]), p3 = f2bf(acc[m][n][3]);
          uint2 pk;
          pk.x = (uint32_t)p0 | ((uint32_t)p1 << 16);
          pk.y = (uint32_t)p2 | ((uint32_t)p3 << 16);
          *(uint2*)(Vto + (size_t)(bh * DH + d) * TT + tt) = pk;
        } else {
          ushort* dstp = (part == 0) ? Qo : Ko;
#pragma unroll
          for (int r = 0; r < 4; ++r)
            dstp[(size_t)(bh * TT + tt + r) * DH + d] = f2bf(acc[m][n][r]);
        }
      }
    }
  }
}

// ---------------- fused causal flash attention ----------------
// Grid: (B*H) * (T/128) blocks, 256 threads (4 waves). Wave w owns q rows [w*32, w*32+32).
// Computes S^T = K @ Q^T so lane regs hold consecutive k; P packed to LDS as 8B writes.
__launch_bounds__(256)
__global__ void attn_kernel(const ushort* __restrict__ Qg, const ushort* __restrict__ Kg,
                            const ushort* __restrict__ Vtg, ushort* __restrict__ Y) {
  __shared__ ushort Ks[64 * 64];
  __shared__ ushort Vs[64 * 64];
  __shared__ ushort Ps[128 * 64];
  const int tid = threadIdx.x;
  const int lane = tid & 63;
  const int w = tid >> 6;
  const int g = lane >> 4, r16 = lane & 15;
  const int bh = blockIdx.x >> 4;   // T/128 = 16 q-tiles per (b,h)
  const int qi = blockIdx.x & 15;
  const int q0 = qi << 7;
  const int b = bh >> 4, h = bh & 15;

  // Q fragments in registers (B-operand layout): q = q0 + w*32 + n*16 + r16, d = dh*32 + g*8..+7
  bf16x8 qf[2][2];
#pragma unroll
  for (int n = 0; n < 2; ++n)
#pragma unroll
    for (int dh = 0; dh < 2; ++dh) {
      int q = q0 + (w << 5) + (n << 4) + r16;
      qf[n][dh] = *(const bf16x8*)(Qg + (size_t)(bh * TT + q) * DH + dh * 32 + g * 8);
    }

  float mrun[2] = {-INFINITY, -INFINITY};
  float lrun[2] = {0.f, 0.f};
  f32x4 oacc[2][4] = {};

  const char* KgB = (const char*)Kg;
  const char* VtB = (const char*)Vtg;
  char* KsB = (char*)Ks;
  char* VsB = (char*)Vs;
  char* PsB = (char*)Ps;

  const int kend = q0 + 128;
  for (int k0 = 0; k0 < kend; k0 += 64) {
    __syncthreads();  // protect K/V LDS from previous iteration's readers
#pragma unroll
    for (int i = 0; i < 2; ++i) {
      int o = (w << 11) + (i << 10) + (lane << 4);
      int row = o >> 7;
      int ch = (o >> 4) & 7;
      int swz = ((ch ^ (row & 7)) << 4);
      gload_lds16(KgB + (size_t)((bh * TT + k0 + row) * DH) * 2 + swz, KsB + o);
      gload_lds16(VtB + (size_t)((bh * DH + row) * TT + k0) * 2 + swz, VsB + o);
    }
    __syncthreads();

    // S^T = K @ Q^T : sacc[m][n] reg r -> k = k0 + m*16 + g*4 + r, q = q0 + w*32 + n*16 + r16
    f32x4 sacc[4][2] = {};
#pragma unroll
    for (int dh = 0; dh < 2; ++dh) {
      bf16x8 kf[4];
#pragma unroll
      for (int m = 0; m < 4; ++m) {
        int row = (m << 4) + r16;
        kf[m] = *(const bf16x8*)(KsB + row * 128 + (((dh * 4 + g) ^ (row & 7)) << 4));
      }
#pragma unroll
      for (int m = 0; m < 4; ++m)
#pragma unroll
        for (int n = 0; n < 2; ++n)
          sacc[m][n] = __builtin_amdgcn_mfma_f32_16x16x32_bf16(kf[m], qf[n][dh], sacc[m][n], 0, 0, 0);
    }

    // scale (1/sqrt(64)=0.125), causal mask, chunk max
    float cm[2] = {-1e30f, -1e30f};
#pragma unroll
    for (int m = 0; m < 4; ++m)
#pragma unroll
      for (int n = 0; n < 2; ++n)
#pragma unroll
        for (int r = 0; r < 4; ++r) {
          float s = sacc[m][n][r] * 0.125f;
          int kg = k0 + (m << 4) + (g << 2) + r;
          int qg = q0 + (w << 5) + (n << 4) + r16;
          if (kg > qg) s = -1e30f;
          sacc[m][n][r] = s;
          cm[n] = fmaxf(cm[n], s);
        }
#pragma unroll
    for (int n = 0; n < 2; ++n) {
      cm[n] = fmaxf(cm[n], __shfl_xor(cm[n], 16));
      cm[n] = fmaxf(cm[n], __shfl_xor(cm[n], 32));
    }
    float mnew[2], fac[2], cs[2] = {0.f, 0.f};
#pragma unroll
    for (int n = 0; n < 2; ++n) {
      mnew[n] = fmaxf(mrun[n], cm[n]);
      fac[n] = exp2f((mrun[n] - mnew[n]) * LOG2E);
    }
    // P = exp(s - mnew), pack 4 consecutive k (regs) -> 8B LDS write
#pragma unroll
    for (int m = 0; m < 4; ++m)
#pragma unroll
      for (int n = 0; n < 2; ++n) {
        ushort p4[4];
#pragma unroll
        for (int r = 0; r < 4; ++r) {
          float p = exp2f((sacc[m][n][r] - mnew[n]) * LOG2E);
          cs[n] += p;
          p4[r] = f2bf(p);
        }
        uint2 pk;
        pk.x = (uint32_t)p4[0] | ((uint32_t)p4[1] << 16);
        pk.y = (uint32_t)p4[2] | ((uint32_t)p4[3] << 16);
        int row = (w << 5) + (n << 4) + r16;           // q (wave-local tile row)
        int ch = ((m << 1) + (g >> 1)) ^ (row & 7);    // swizzled 16B chunk
        *(uint2*)(PsB + row * 128 + (ch << 4) + ((g & 1) << 3)) = pk;
      }
#pragma unroll
    for (int n = 0; n < 2; ++n) {
      cs[n] += __shfl_xor(cs[n], 16);
      cs[n] += __shfl_xor(cs[n], 32);
      lrun[n] = lrun[n] * fac[n] + cs[n];
      mrun[n] = mnew[n];
    }
    // redistribute rescale factor to O-layout lanes, rescale O
    float facO[2][4];
#pragma unroll
    for (int mq = 0; mq < 2; ++mq)
#pragma unroll
      for (int r = 0; r < 4; ++r)
        facO[mq][r] = __shfl(fac[mq], (g << 2) + r);
#pragma unroll
    for (int mq = 0; mq < 2; ++mq)
#pragma unroll
      for (int nd = 0; nd < 4; ++nd)
#pragma unroll
        for (int r = 0; r < 4; ++r)
          oacc[mq][nd][r] *= facO[mq][r];
    // PV: oacc[mq][nd] += P[q][k] * Vt[d][k]
#pragma unroll
    for (int ks = 0; ks < 2; ++ks) {
      bf16x8 pa[2], vb[4];
#pragma unroll
      for (int mq = 0; mq < 2; ++mq) {
        int row = (w << 5) + (mq << 4) + r16;
        pa[mq] = *(const bf16x8*)(PsB + row * 128 + (((ks * 4 + g) ^ (row & 7)) << 4));
      }
#pragma unroll
      for (int nd = 0; nd < 4; ++nd) {
        int row = (nd << 4) + r16;
        vb[nd] = *(const bf16x8*)(VsB + row * 128 + (((ks * 4 + g) ^ (row & 7)) << 4));
      }
#pragma unroll
      for (int mq = 0; mq < 2; ++mq)
#pragma unroll
        for (int nd = 0; nd < 4; ++nd)
          oacc[mq][nd] = __builtin_amdgcn_mfma_f32_16x16x32_bf16(pa[mq], vb[nd], oacc[mq][nd], 0, 0, 0);
    }
  }

  // normalize + store Y[b][t][h*64+d] bf16
  float inv[2][4];
#pragma unroll
  for (int mq = 0; mq < 2; ++mq) {
    float iv = 1.0f / lrun[mq];
#pragma unroll
    for (int r = 0; r < 4; ++r) inv[mq][r] = __shfl(iv, (g << 2) + r);
  }
#pragma unroll
  for (int mq = 0; mq < 2; ++mq)
#pragma unroll
    for (int nd = 0; nd < 4; ++nd)
#pragma unroll
      for (int r = 0; r < 4; ++r) {
        int t = q0 + (w << 5) + (mq << 4) + (g << 2) + r;
        int col = h * DH + (nd << 4) + r16;
        Y[(size_t)(b * TT + t) * DM + col] = f2bf(oacc[mq][nd][r] * inv[mq][r]);
      }
}

// ---------------- launch ----------------
extern "C" void kernel_launch(void* const* d_in, const int* in_sizes, int n_in,
                              void* d_out, int out_size, void* d_ws, size_t ws_size,
                              hipStream_t stream) {
  const float* x = (const float*)d_in[0];
  // d_in[1] = mask (int32 tril) -- causal structure is known, unused
  const float* w_qkv = (const float*)d_in[2];
  const float* w_out = (const float*)d_in[3];
  float* out = (float*)d_out;

  char* ws = (char*)d_ws;
  ushort* Xb  = (ushort*)(ws);                        // [4096,1024] bf16   8 MiB
  ushort* Wqt = (ushort*)(ws + (8ull << 20));         // [3072,1024] bf16   6 MiB
  ushort* Wot = (ushort*)(ws + (14ull << 20));        // [1024,1024] bf16   2 MiB
  ushort* Qv  = (ushort*)(ws + (16ull << 20));        // [B,H,T,Dh] bf16    8 MiB
  ushort* Kv  = (ushort*)(ws + (24ull << 20));        // [B,H,T,Dh] bf16    8 MiB
  ushort* Vt  = (ushort*)(ws + (32ull << 20));        // [B,H,Dh,T] bf16    8 MiB
  ushort* Yb  = Xb;  // alias: Xb is dead after the QKV GEMM; attn writes Yb after it completes

  // 1) cast x -> bf16
  cast4_kernel<<<(TB * TT * DM / 4 + 255) / 256, 256, 0, stream>>>(x, Xb, TB * TT * DM / 4);
  // 2) transpose-cast weights to B^T form
  transpose_cast_kernel<<<dim3(3 * DM / 32, DM / 32), dim3(32, 8), 0, stream>>>(w_qkv, Wqt, DM, 3 * DM);
  transpose_cast_kernel<<<dim3(DM / 32, DM / 32), dim3(32, 8), 0, stream>>>(w_out, Wot, DM, DM);
  // 3) QKV projection with split-heads scatter (V transposed)
  gemm_bt_kernel<1><<<(TB * TT / 128) * (3 * DM / 128), 256, 0, stream>>>(
      Xb, Wqt, nullptr, Qv, Kv, Vt, TB * TT, 3 * DM, DM);
  // 4) fused causal attention -> Y [4096,1024] bf16
  attn_kernel<<<TB * NH * (TT / 128), 256, 0, stream>>>(Qv, Kv, Vt, Yb);
  // 5) output projection -> fp32 out
  gemm_bt_kernel<0><<<(TB * TT / 128) * (DM / 128), 256, 0, stream>>>(
      Yb, Wot, out, nullptr, nullptr, nullptr, TB * TT, DM, DM);
}

// Round 3
// 211.594 us; speedup vs baseline: 1.2184x; 1.2184x over previous
//
#include <hip/hip_runtime.h>
#include <stdint.h>

// Problem constants (from reference): B=2, T=2048, D_MODEL=1024, H=16, Dh=64
#define TB 2
#define TT 2048
#define DM 1024
#define NH 16
#define DH 64

typedef __bf16 bf16x8 __attribute__((ext_vector_type(8)));
typedef __bf16 bf16x2 __attribute__((ext_vector_type(2)));
typedef float f32x4 __attribute__((ext_vector_type(4)));

#define LOG2E 1.4426950408889634f
// Q pre-scale: fold 1/sqrt(Dh) and log2(e) so softmax runs in base-2 domain
#define QSCALE (0.125f * LOG2E)

__device__ __forceinline__ ushort f2bf(float f) {
  uint32_t u = __builtin_bit_cast(uint32_t, f);
  u += 0x7FFFu + ((u >> 16) & 1u);
  return (ushort)(u >> 16);
}

__device__ __forceinline__ uint32_t pk_bf16(float lo, float hi) {
  bf16x2 t;
  t[0] = (__bf16)lo;
  t[1] = (__bf16)hi;
  return __builtin_bit_cast(uint32_t, t);
}

__device__ __forceinline__ void gload_lds16(const void* g, void* l) {
  __builtin_amdgcn_global_load_lds(
      (__attribute__((address_space(1))) void*)g,
      (__attribute__((address_space(3))) void*)l, 16, 0, 0);
}

// ---------------- cast x fp32 -> bf16 (vectorized x4) ----------------
__global__ void cast4_kernel(const float* __restrict__ in, ushort* __restrict__ out, int n4) {
  int i = blockIdx.x * blockDim.x + threadIdx.x;
  if (i < n4) {
    float4 v = ((const float4*)in)[i];
    ushort4 o;
    o.x = f2bf(v.x); o.y = f2bf(v.y); o.z = f2bf(v.z); o.w = f2bf(v.w);
    ((ushort4*)out)[i] = o;
  }
}

// ---------------- transpose + cast: w[K][N] fp32 -> wt[N][K] bf16 ----------------
__global__ void transpose_cast_kernel(const float* __restrict__ w, ushort* __restrict__ wt,
                                      int K, int N) {
  __shared__ float tile[32][33];
  int n0 = blockIdx.x * 32, k0 = blockIdx.y * 32;
  int tx = threadIdx.x, ty = threadIdx.y;  // (32, 8)
#pragma unroll
  for (int i = 0; i < 4; ++i)
    tile[ty + i * 8][tx] = w[(size_t)(k0 + ty + i * 8) * N + n0 + tx];
  __syncthreads();
#pragma unroll
  for (int i = 0; i < 4; ++i)
    wt[(size_t)(n0 + ty + i * 8) * K + k0 + tx] = f2bf(tile[tx][ty + i * 8]);
}

// ---------------- GEMM: C = A[M,K] @ Bt[N,K]^T, bf16 in / fp32 accum ----------------
// 128x128 tile, BK=32, 4 waves each 64x64 (4x4 frags of 16x16x32).
// EPI 0: fp32 out [M,N].  EPI 1: QKV scatter (Q*QSCALE,K -> [b,h,t,d] bf16; V -> [b,h,d,t] bf16).
template <int EPI>
__launch_bounds__(256)
__global__ void gemm_bt_kernel(const ushort* __restrict__ A, const ushort* __restrict__ Bt,
                               float* __restrict__ outF, ushort* __restrict__ Qo,
                               ushort* __restrict__ Ko, ushort* __restrict__ Vto,
                               int M, int N, int K) {
  __shared__ ushort As[128 * 32];
  __shared__ ushort Bs[128 * 32];
  const int tid = threadIdx.x;
  const int lane = tid & 63;
  const int w = tid >> 6;
  const int nb = N >> 7;
  const int bx = blockIdx.x % nb, by = blockIdx.x / nb;
  const int m0 = by << 7, n0 = bx << 7;
  const int wr = (w >> 1) << 6, wc = (w & 1) << 6;
  const int g = lane >> 4, r16 = lane & 15;

  f32x4 acc[4][4] = {};

  const char* Ab = (const char*)A;
  const char* Bb = (const char*)Bt;
  char* AsB = (char*)As;
  char* BsB = (char*)Bs;

  for (int k0 = 0; k0 < K; k0 += 32) {
#pragma unroll
    for (int i = 0; i < 2; ++i) {
      int o = (w << 11) + (i << 10) + (lane << 4);
      int row = o >> 6;
      int ch = (o >> 4) & 3;
      int chl = ch ^ ((row >> 1) & 3);  // logical chunk (inverse-swizzled source)
      gload_lds16(Ab + (size_t)((m0 + row) * K + k0) * 2 + (chl << 4), AsB + o);
      gload_lds16(Bb + (size_t)((n0 + row) * K + k0) * 2 + (chl << 4), BsB + o);
    }
    __syncthreads();

    bf16x8 af[4], bfr[4];
#pragma unroll
    for (int m = 0; m < 4; ++m) {
      int rowA = wr + (m << 4) + r16;
      af[m] = *(const bf16x8*)(AsB + rowA * 64 + ((g ^ ((rowA >> 1) & 3)) << 4));
      int rowB = wc + (m << 4) + r16;
      bfr[m] = *(const bf16x8*)(BsB + rowB * 64 + ((g ^ ((rowB >> 1) & 3)) << 4));
    }
#pragma unroll
    for (int m = 0; m < 4; ++m)
#pragma unroll
      for (int n = 0; n < 4; ++n)
        acc[m][n] = __builtin_amdgcn_mfma_f32_16x16x32_bf16(af[m], bfr[n], acc[m][n], 0, 0, 0);
    __syncthreads();
  }

  if (EPI == 0) {
#pragma unroll
    for (int m = 0; m < 4; ++m)
#pragma unroll
      for (int n = 0; n < 4; ++n)
#pragma unroll
        for (int r = 0; r < 4; ++r) {
          int row = m0 + wr + (m << 4) + (g << 2) + r;
          int col = n0 + wc + (n << 4) + r16;
          outF[(size_t)row * N + col] = acc[m][n][r];
        }
  } else {
    const int colBase = n0 + wc;
#pragma unroll
    for (int m = 0; m < 4; ++m) {
      int trow = m0 + wr + (m << 4) + (g << 2);  // t base for r=0 (b uniform per block)
      int b = trow >> 11;
      int tt = trow & (TT - 1);
#pragma unroll
      for (int n = 0; n < 4; ++n) {
        int e = colBase + (n << 4) + r16;
        int part = e >> 10;
        int rem = e & 1023;
        int h = rem >> 6, d = rem & 63;
        int bh = b * NH + h;
        if (part == 2) {
          ushort p0 = f2bf(acc[m][n][0]), p1 = f2bf(acc[m][n][1]);
          ushort p2 = f2bf(acc[m][n][2]), p3 = f2bf(acc[m][n][3]);
          uint2 pk;
          pk.x = (uint32_t)p0 | ((uint32_t)p1 << 16);
          pk.y = (uint32_t)p2 | ((uint32_t)p3 << 16);
          *(uint2*)(Vto + (size_t)(bh * DH + d) * TT + tt) = pk;
        } else {
          ushort* dstp = (part == 0) ? Qo : Ko;
          float sc = (part == 0) ? QSCALE : 1.0f;
#pragma unroll
          for (int r = 0; r < 4; ++r)
            dstp[(size_t)(bh * TT + tt + r) * DH + d] = f2bf(acc[m][n][r] * sc);
        }
      }
    }
  }
}

// ---------------- fused causal flash attention (v2) ----------------
// Grid: 512 blocks, 512 threads (8 waves). Block handles 128 q-rows; wave w owns 16 rows.
// Longest-first order: qi = 15 - (bidx>>5). Q is pre-scaled by QSCALE (base-2 softmax).
// Computes S^T = K @ Q^T so lane regs hold consecutive k; P packed to LDS as 8B writes.
__launch_bounds__(512)
__global__ void attn_kernel(const ushort* __restrict__ Qg, const ushort* __restrict__ Kg,
                            const ushort* __restrict__ Vtg, ushort* __restrict__ Y) {
  __shared__ ushort Ks[64 * 64];
  __shared__ ushort Vs[64 * 64];
  __shared__ ushort Ps[128 * 64];
  const int tid = threadIdx.x;
  const int lane = tid & 63;
  const int w = tid >> 6;          // 0..7
  const int g = lane >> 4, r16 = lane & 15;
  const int bidx = blockIdx.x;
  const int qi = 15 - (bidx >> 5); // longest blocks launch first (LPT)
  const int bh = bidx & 31;
  const int q0 = qi << 7;
  const int b = bh >> 4, h = bh & 15;
  const int qw = q0 + (w << 4);    // wave's first q row

  // Q fragments (B-operand layout): q = qw + r16, d = dh*32 + g*8 .. +7
  bf16x8 qf[2];
#pragma unroll
  for (int dh = 0; dh < 2; ++dh)
    qf[dh] = *(const bf16x8*)(Qg + (size_t)(bh * TT + qw + r16) * DH + dh * 32 + g * 8);

  float mrun = -INFINITY;
  float lrun = 0.f;
  f32x4 oacc[4] = {};

  const char* KgB = (const char*)Kg;
  const char* VtB = (const char*)Vtg;
  char* KsB = (char*)Ks;
  char* VsB = (char*)Vs;
  char* PsB = (char*)Ps;

  const int kend = q0 + 128;
  for (int k0 = 0; k0 < kend; k0 += 64) {
    __syncthreads();  // protect K/V LDS from previous iteration's readers
    {
      int o = tid << 4;               // 512 threads x 16B = full 8KB chunk
      int row = o >> 7;               // K: k row 0..63 | V: d row 0..63
      int chl = ((o >> 4) & 7) ^ (row & 7);  // inverse-swizzled source chunk
      gload_lds16(KgB + (size_t)(bh * TT + k0 + row) * 128 + (chl << 4), KsB + o);
      gload_lds16(VtB + (size_t)(bh * DH + row) * (TT * 2) + k0 * 2 + (chl << 4), VsB + o);
    }
    __syncthreads();

    if (k0 <= qw + 15) {  // wave-uniform: skip fully-masked chunks
      // S^T = K @ Q^T : sacc[m] reg r -> k = k0 + m*16 + g*4 + r, q = qw + r16
      f32x4 sacc[4] = {};
#pragma unroll
      for (int dh = 0; dh < 2; ++dh) {
        bf16x8 kf[4];
#pragma unroll
        for (int m = 0; m < 4; ++m) {
          int row = (m << 4) + r16;
          kf[m] = *(const bf16x8*)(KsB + row * 128 + ((((dh << 2) + g) ^ (row & 7)) << 4));
        }
#pragma unroll
        for (int m = 0; m < 4; ++m)
          sacc[m] = __builtin_amdgcn_mfma_f32_16x16x32_bf16(kf[m], qf[dh], sacc[m], 0, 0, 0);
      }

      float cm = -1e30f;
      if (k0 + 63 > qw) {  // diagonal chunk: per-element causal mask (wave-uniform branch)
        const int qg = qw + r16;
#pragma unroll
        for (int m = 0; m < 4; ++m)
#pragma unroll
          for (int r = 0; r < 4; ++r) {
            int kg = k0 + (m << 4) + (g << 2) + r;
            float s = sacc[m][r];
            s = (kg > qg) ? -1e30f : s;
            sacc[m][r] = s;
            cm = fmaxf(cm, s);
          }
      } else {
#pragma unroll
        for (int m = 0; m < 4; ++m)
#pragma unroll
          for (int r = 0; r < 4; ++r) cm = fmaxf(cm, sacc[m][r]);
      }
      cm = fmaxf(cm, __shfl_xor(cm, 16));
      cm = fmaxf(cm, __shfl_xor(cm, 32));

      float mnew = fmaxf(mrun, cm);
      float fac = exp2f(mrun - mnew);
      float cs = 0.f;
      const int prow = (w << 4) + r16;
#pragma unroll
      for (int m = 0; m < 4; ++m) {
        float p0 = exp2f(sacc[m][0] - mnew);
        float p1 = exp2f(sacc[m][1] - mnew);
        float p2 = exp2f(sacc[m][2] - mnew);
        float p3 = exp2f(sacc[m][3] - mnew);
        cs += (p0 + p1) + (p2 + p3);
        uint2 pk;
        pk.x = pk_bf16(p0, p1);
        pk.y = pk_bf16(p2, p3);
        int ch = ((m << 1) + (g >> 1)) ^ (prow & 7);
        *(uint2*)(PsB + prow * 128 + (ch << 4) + ((g & 1) << 3)) = pk;
      }
      cs += __shfl_xor(cs, 16);
      cs += __shfl_xor(cs, 32);
      lrun = lrun * fac + cs;
      mrun = mnew;

      // rescale O (fac redistributed to O-layout lanes)
      float facO[4];
#pragma unroll
      for (int r = 0; r < 4; ++r) facO[r] = __shfl(fac, (g << 2) + r);
#pragma unroll
      for (int nd = 0; nd < 4; ++nd)
#pragma unroll
        for (int r = 0; r < 4; ++r) oacc[nd][r] *= facO[r];

      // PV: oacc[nd] += P[q][k] * Vt[d][k]
#pragma unroll
      for (int ks = 0; ks < 2; ++ks) {
        bf16x8 pa = *(const bf16x8*)(PsB + prow * 128 + ((((ks << 2) + g) ^ (prow & 7)) << 4));
        bf16x8 vb[4];
#pragma unroll
        for (int nd = 0; nd < 4; ++nd) {
          int vrow = (nd << 4) + r16;
          vb[nd] = *(const bf16x8*)(VsB + vrow * 128 + ((((ks << 2) + g) ^ (vrow & 7)) << 4));
        }
#pragma unroll
        for (int nd = 0; nd < 4; ++nd)
          oacc[nd] = __builtin_amdgcn_mfma_f32_16x16x32_bf16(pa, vb[nd], oacc[nd], 0, 0, 0);
      }
    }
  }

  // normalize + store Y[b][t][h*64+d] bf16
  float inv = 1.0f / lrun;
  float invO[4];
#pragma unroll
  for (int r = 0; r < 4; ++r) invO[r] = __shfl(inv, (g << 2) + r);
#pragma unroll
  for (int nd = 0; nd < 4; ++nd)
#pragma unroll
    for (int r = 0; r < 4; ++r) {
      int t = q0 + (w << 4) + (g << 2) + r;
      int col = h * DH + (nd << 4) + r16;
      Y[(size_t)(b * TT + t) * DM + col] = f2bf(oacc[nd][r] * invO[r]);
    }
}

// ---------------- launch ----------------
extern "C" void kernel_launch(void* const* d_in, const int* in_sizes, int n_in,
                              void* d_out, int out_size, void* d_ws, size_t ws_size,
                              hipStream_t stream) {
  const float* x = (const float*)d_in[0];
  // d_in[1] = mask (int32 tril) -- causal structure is known, unused
  const float* w_qkv = (const float*)d_in[2];
  const float* w_out = (const float*)d_in[3];
  float* out = (float*)d_out;

  char* ws = (char*)d_ws;
  ushort* Xb  = (ushort*)(ws);                        // [4096,1024] bf16   8 MiB
  ushort* Wqt = (ushort*)(ws + (8ull << 20));         // [3072,1024] bf16   6 MiB
  ushort* Wot = (ushort*)(ws + (14ull << 20));        // [1024,1024] bf16   2 MiB
  ushort* Qv  = (ushort*)(ws + (16ull << 20));        // [B,H,T,Dh] bf16    8 MiB
  ushort* Kv  = (ushort*)(ws + (24ull << 20));        // [B,H,T,Dh] bf16    8 MiB
  ushort* Vt  = (ushort*)(ws + (32ull << 20));        // [B,H,Dh,T] bf16    8 MiB
  ushort* Yb  = Xb;  // alias: Xb is dead after the QKV GEMM

  // 1) cast x -> bf16
  cast4_kernel<<<(TB * TT * DM / 4 + 255) / 256, 256, 0, stream>>>(x, Xb, TB * TT * DM / 4);
  // 2) transpose-cast weights to B^T form
  transpose_cast_kernel<<<dim3(3 * DM / 32, DM / 32), dim3(32, 8), 0, stream>>>(w_qkv, Wqt, DM, 3 * DM);
  transpose_cast_kernel<<<dim3(DM / 32, DM / 32), dim3(32, 8), 0, stream>>>(w_out, Wot, DM, DM);
  // 3) QKV projection with split-heads scatter (Q pre-scaled; V transposed)
  gemm_bt_kernel<1><<<(TB * TT / 128) * (3 * DM / 128), 256, 0, stream>>>(
      Xb, Wqt, nullptr, Qv, Kv, Vt, TB * TT, 3 * DM, DM);
  // 4) fused causal attention -> Y [4096,1024] bf16
  attn_kernel<<<TB * NH * (TT / 128), 512, 0, stream>>>(Qv, Kv, Vt, Yb);
  // 5) output projection -> fp32 out
  gemm_bt_kernel<0><<<(TB * TT / 128) * (DM / 128), 256, 0, stream>>>(
      Yb, Wot, out, nullptr, nullptr, nullptr, TB * TT, DM, DM);
}

// Round 6
// 201.587 us; speedup vs baseline: 1.2789x; 1.0496x over previous
//
#include <hip/hip_runtime.h>
#include <stdint.h>

// Problem constants (from reference): B=2, T=2048, D_MODEL=1024, H=16, Dh=64
#define TB 2
#define TT 2048
#define DM 1024
#define NH 16
#define DH 64

typedef __bf16 bf16x8 __attribute__((ext_vector_type(8)));
typedef __bf16 bf16x2 __attribute__((ext_vector_type(2)));
typedef float f32x4 __attribute__((ext_vector_type(4)));

#define LOG2E 1.4426950408889634f
// Q pre-scale: fold 1/sqrt(Dh) and log2(e) so softmax runs in base-2 domain
#define QSCALE (0.125f * LOG2E)

__device__ __forceinline__ ushort f2bf(float f) {
  uint32_t u = __builtin_bit_cast(uint32_t, f);
  u += 0x7FFFu + ((u >> 16) & 1u);
  return (ushort)(u >> 16);
}

__device__ __forceinline__ uint32_t pk_bf16(float lo, float hi) {
  bf16x2 t;
  t[0] = (__bf16)lo;
  t[1] = (__bf16)hi;
  return __builtin_bit_cast(uint32_t, t);
}

__device__ __forceinline__ void gload_lds16(const void* g, void* l) {
  __builtin_amdgcn_global_load_lds(
      (__attribute__((address_space(1))) void*)g,
      (__attribute__((address_space(3))) void*)l, 16, 0, 0);
}

// ---------------- cast x fp32 -> bf16 (vectorized x4) ----------------
__global__ void cast4_kernel(const float* __restrict__ in, ushort* __restrict__ out, int n4) {
  int i = blockIdx.x * blockDim.x + threadIdx.x;
  if (i < n4) {
    float4 v = ((const float4*)in)[i];
    ushort4 o;
    o.x = f2bf(v.x); o.y = f2bf(v.y); o.z = f2bf(v.z); o.w = f2bf(v.w);
    ((ushort4*)out)[i] = o;
  }
}

// ---------------- transpose + cast: w[K][N] fp32 -> wt[N][K] bf16 ----------------
__global__ void transpose_cast_kernel(const float* __restrict__ w, ushort* __restrict__ wt,
                                      int K, int N) {
  __shared__ float tile[32][33];
  int n0 = blockIdx.x * 32, k0 = blockIdx.y * 32;
  int tx = threadIdx.x, ty = threadIdx.y;  // (32, 8)
#pragma unroll
  for (int i = 0; i < 4; ++i)
    tile[ty + i * 8][tx] = w[(size_t)(k0 + ty + i * 8) * N + n0 + tx];
  __syncthreads();
#pragma unroll
  for (int i = 0; i < 4; ++i)
    wt[(size_t)(n0 + ty + i * 8) * K + k0 + tx] = f2bf(tile[tx][ty + i * 8]);
}

// ---------------- GEMM: C = A[M,K] @ Bt[N,K]^T, bf16 in / fp32 accum ----------------
// 128x128 tile, BK=32, 4 waves each 64x64 (4x4 frags of 16x16x32).
// Double-buffered LDS, single barrier per K-step: stage(next) overlaps compute(cur).
// EPI 0: fp32 out [M,N].  EPI 1: QKV scatter (Q*QSCALE,K -> [b,h,t,d] bf16; V -> [b,h,d,t] bf16).
template <int EPI>
__launch_bounds__(256)
__global__ void gemm_bt_kernel(const ushort* __restrict__ A, const ushort* __restrict__ Bt,
                               float* __restrict__ outF, ushort* __restrict__ Qo,
                               ushort* __restrict__ Ko, ushort* __restrict__ Vto,
                               int M, int N, int K) {
  __shared__ ushort As[2 * 128 * 32];
  __shared__ ushort Bs[2 * 128 * 32];
  const int tid = threadIdx.x;
  const int lane = tid & 63;
  const int w = tid >> 6;
  const int nb = N >> 7;
  const int bx = blockIdx.x % nb, by = blockIdx.x / nb;
  const int m0 = by << 7, n0 = bx << 7;
  const int wr = (w >> 1) << 6, wc = (w & 1) << 6;
  const int g = lane >> 4, r16 = lane & 15;

  f32x4 acc[4][4] = {};

  const char* Ab = (const char*)A;
  const char* Bb = (const char*)Bt;
  char* AsB = (char*)As;
  char* BsB = (char*)Bs;

  auto stage = [&](int buf, int k0) {
#pragma unroll
    for (int i = 0; i < 2; ++i) {
      int o = (w << 11) + (i << 10) + (lane << 4);
      int row = o >> 6;
      int chl = ((o >> 4) & 3) ^ ((row >> 1) & 3);  // inverse-swizzled source chunk
      gload_lds16(Ab + (size_t)((m0 + row) * K + k0) * 2 + (chl << 4), AsB + (buf << 13) + o);
      gload_lds16(Bb + (size_t)((n0 + row) * K + k0) * 2 + (chl << 4), BsB + (buf << 13) + o);
    }
  };

  const int NK = K >> 5;
  stage(0, 0);
  for (int kt = 0; kt < NK; ++kt) {
    const int cur = kt & 1;
    __syncthreads();  // drains own staging of buf[cur]; prior reads of buf[cur^1] already done
    if (kt + 1 < NK) stage(cur ^ 1, (kt + 1) << 5);

    const char* Ac = AsB + (cur << 13);
    const char* Bc = BsB + (cur << 13);
    bf16x8 af[4], bfr[4];
#pragma unroll
    for (int m = 0; m < 4; ++m) {
      int rowA = wr + (m << 4) + r16;
      af[m] = *(const bf16x8*)(Ac + rowA * 64 + ((g ^ ((rowA >> 1) & 3)) << 4));
      int rowB = wc + (m << 4) + r16;
      bfr[m] = *(const bf16x8*)(Bc + rowB * 64 + ((g ^ ((rowB >> 1) & 3)) << 4));
    }
#pragma unroll
    for (int m = 0; m < 4; ++m)
#pragma unroll
      for (int n = 0; n < 4; ++n)
        acc[m][n] = __builtin_amdgcn_mfma_f32_16x16x32_bf16(af[m], bfr[n], acc[m][n], 0, 0, 0);
  }

  if (EPI == 0) {
#pragma unroll
    for (int m = 0; m < 4; ++m)
#pragma unroll
      for (int n = 0; n < 4; ++n)
#pragma unroll
        for (int r = 0; r < 4; ++r) {
          int row = m0 + wr + (m << 4) + (g << 2) + r;
          int col = n0 + wc + (n << 4) + r16;
          outF[(size_t)row * N + col] = acc[m][n][r];
        }
  } else {
    const int colBase = n0 + wc;
#pragma unroll
    for (int m = 0; m < 4; ++m) {
      int trow = m0 + wr + (m << 4) + (g << 2);  // t base for r=0 (b uniform per block)
      int b = trow >> 11;
      int tt = trow & (TT - 1);
#pragma unroll
      for (int n = 0; n < 4; ++n) {
        int e = colBase + (n << 4) + r16;
        int part = e >> 10;
        int rem = e & 1023;
        int h = rem >> 6, d = rem & 63;
        int bh = b * NH + h;
        if (part == 2) {
          ushort p0 = f2bf(acc[m][n][0]), p1 = f2bf(acc[m][n][1]);
          ushort p2 = f2bf(acc[m][n][2]), p3 = f2bf(acc[m][n][3]);
          uint2 pk;
          pk.x = (uint32_t)p0 | ((uint32_t)p1 << 16);
          pk.y = (uint32_t)p2 | ((uint32_t)p3 << 16);
          *(uint2*)(Vto + (size_t)(bh * DH + d) * TT + tt) = pk;
        } else {
          ushort* dstp = (part == 0) ? Qo : Ko;
          float sc = (part == 0) ? QSCALE : 1.0f;
#pragma unroll
          for (int r = 0; r < 4; ++r)
            dstp[(size_t)(bh * TT + tt + r) * DH + d] = f2bf(acc[m][n][r] * sc);
        }
      }
    }
  }
}

// ---------------- fused causal flash attention (v3) ----------------
// Grid: 512 blocks, 512 threads (8 waves). Block handles 128 q-rows; wave w owns 16 rows.
// KVBLK=128 (one barrier pair per 128 k). Longest-first order. Q pre-scaled (base-2 softmax).
// S^T = K @ Q^T (lane regs = consecutive k); defer-rescale THR=8; setprio around MFMA.
__launch_bounds__(512, 4)
__global__ void attn_kernel(const ushort* __restrict__ Qg, const ushort* __restrict__ Kg,
                            const ushort* __restrict__ Vtg, ushort* __restrict__ Y) {
  __shared__ ushort Ks[128 * 64];   // [k][d]  row 128B,  8 chunks, swz ^(row&7)
  __shared__ ushort Vs[64 * 128];   // [d][k]  row 256B, 16 chunks, swz ^(row&15)
  __shared__ ushort Ps[128 * 128];  // [q][k]  row 256B, 16 chunks, swz ^(row&15)
  const int tid = threadIdx.x;
  const int lane = tid & 63;
  const int w = tid >> 6;          // 0..7
  const int g = lane >> 4, r16 = lane & 15;
  const int bidx = blockIdx.x;
  const int qi = 15 - (bidx >> 5); // longest blocks launch first (LPT)
  const int bh = bidx & 31;
  const int q0 = qi << 7;
  const int b = bh >> 4, h = bh & 15;
  const int qw = q0 + (w << 4);    // wave's first q row
  const int prow = (w << 4) + r16; // this lane's P row (q-local)

  // Q fragments (B-operand layout): q = qw + r16, d = dh*32 + g*8 .. +7
  bf16x8 qf[2];
#pragma unroll
  for (int dh = 0; dh < 2; ++dh)
    qf[dh] = *(const bf16x8*)(Qg + (size_t)(bh * TT + qw + r16) * DH + dh * 32 + g * 8);

  float mrun = -INFINITY;
  float lrun = 0.f;
  f32x4 oacc[4] = {};

  const char* KgB = (const char*)Kg;
  const char* VtB = (const char*)Vtg;
  char* KsB = (char*)Ks;
  char* VsB = (char*)Vs;
  char* PsB = (char*)Ps;

  for (int c = 0; c <= qi; ++c) {
    const int k0 = c << 7;
    __syncthreads();  // protect K/V LDS from previous iteration's readers
#pragma unroll
    for (int i = 0; i < 2; ++i) {
      int o = (tid << 4) + (i << 13);       // 512 thr x 2 x 16B = 16KB each
      int krow = o >> 7;
      int kchl = ((o >> 4) & 7) ^ (krow & 7);
      gload_lds16(KgB + (size_t)(bh * TT + k0 + krow) * 128 + (kchl << 4), KsB + o);
      int vrow = o >> 8;
      int vchl = ((o >> 4) & 15) ^ (vrow & 15);
      gload_lds16(VtB + (size_t)(bh * DH + vrow) * 4096 + k0 * 2 + (vchl << 4), VsB + o);
    }
    __syncthreads();

    // S^T = K @ Q^T : sacc[m] reg r -> k = k0 + m*16 + g*4 + r, q = qw + r16
    f32x4 sacc[8] = {};
    __builtin_amdgcn_s_setprio(1);
#pragma unroll
    for (int dh = 0; dh < 2; ++dh) {
#pragma unroll
      for (int m = 0; m < 8; ++m) {
        int krow = (m << 4) + r16;
        bf16x8 kf = *(const bf16x8*)(KsB + krow * 128 + ((((dh << 2) + g) ^ (krow & 7)) << 4));
        sacc[m] = __builtin_amdgcn_mfma_f32_16x16x32_bf16(kf, qf[dh], sacc[m], 0, 0, 0);
      }
    }
    __builtin_amdgcn_s_setprio(0);

    float cm = -1e30f;
    if (c == qi) {  // the single diagonal chunk for every wave: per-element causal mask
      const int qg = qw + r16;
#pragma unroll
      for (int m = 0; m < 8; ++m)
#pragma unroll
        for (int r = 0; r < 4; ++r) {
          int kg = k0 + (m << 4) + (g << 2) + r;
          float s = sacc[m][r];
          s = (kg > qg) ? -1e30f : s;
          sacc[m][r] = s;
          cm = fmaxf(cm, s);
        }
    } else {
#pragma unroll
      for (int m = 0; m < 8; ++m)
#pragma unroll
        for (int r = 0; r < 4; ++r) cm = fmaxf(cm, sacc[m][r]);
    }
    cm = fmaxf(cm, __shfl_xor(cm, 16));
    cm = fmaxf(cm, __shfl_xor(cm, 32));

    // defer-rescale (T13): skip O-rescale while chunk max stays within 2^8 of running max
    if (!__all(cm <= mrun + 8.f)) {
      float mnew = fmaxf(mrun, cm);
      float fac = exp2f(mrun - mnew);
      lrun *= fac;
      mrun = mnew;
      float facO[4];
#pragma unroll
      for (int r = 0; r < 4; ++r) facO[r] = __shfl(fac, (g << 2) + r);
#pragma unroll
      for (int nd = 0; nd < 4; ++nd)
#pragma unroll
        for (int r = 0; r < 4; ++r) oacc[nd][r] *= facO[r];
    }

    // P = 2^(s - mrun), pack 4 consecutive k -> 8B LDS write
    float cs = 0.f;
#pragma unroll
    for (int m = 0; m < 8; ++m) {
      float p0 = exp2f(sacc[m][0] - mrun);
      float p1 = exp2f(sacc[m][1] - mrun);
      float p2 = exp2f(sacc[m][2] - mrun);
      float p3 = exp2f(sacc[m][3] - mrun);
      cs += (p0 + p1) + (p2 + p3);
      uint2 pk;
      pk.x = pk_bf16(p0, p1);
      pk.y = pk_bf16(p2, p3);
      int ch = ((m << 1) + (g >> 1)) ^ (prow & 15);
      *(uint2*)(PsB + prow * 256 + (ch << 4) + ((g & 1) << 3)) = pk;
    }
    cs += __shfl_xor(cs, 16);
    cs += __shfl_xor(cs, 32);
    lrun += cs;

    // PV: oacc[nd] += P[q][k] * Vt[d][k]
    __builtin_amdgcn_s_setprio(1);
#pragma unroll
    for (int ks = 0; ks < 4; ++ks) {
      bf16x8 pa = *(const bf16x8*)(PsB + prow * 256 + ((((ks << 2) + g) ^ (prow & 15)) << 4));
      bf16x8 vb[4];
#pragma unroll
      for (int nd = 0; nd < 4; ++nd) {
        int vrow = (nd << 4) + r16;
        vb[nd] = *(const bf16x8*)(VsB + vrow * 256 + ((((ks << 2) + g) ^ (vrow & 15)) << 4));
      }
#pragma unroll
      for (int nd = 0; nd < 4; ++nd)
        oacc[nd] = __builtin_amdgcn_mfma_f32_16x16x32_bf16(pa, vb[nd], oacc[nd], 0, 0, 0);
    }
    __builtin_amdgcn_s_setprio(0);
  }

  // normalize + store Y[b][t][h*64+d] bf16
  float inv = 1.0f / lrun;
  float invO[4];
#pragma unroll
  for (int r = 0; r < 4; ++r) invO[r] = __shfl(inv, (g << 2) + r);
#pragma unroll
  for (int nd = 0; nd < 4; ++nd)
#pragma unroll
    for (int r = 0; r < 4; ++r) {
      int t = q0 + (w << 4) + (g << 2) + r;
      int col = h * DH + (nd << 4) + r16;
      Y[(size_t)(b * TT + t) * DM + col] = f2bf(oacc[nd][r] * invO[r]);
    }
}

// ---------------- launch ----------------
extern "C" void kernel_launch(void* const* d_in, const int* in_sizes, int n_in,
                              void* d_out, int out_size, void* d_ws, size_t ws_size,
                              hipStream_t stream) {
  const float* x = (const float*)d_in[0];
  // d_in[1] = mask (int32 tril) -- causal structure is known, unused
  const float* w_qkv = (const float*)d_in[2];
  const float* w_out = (const float*)d_in[3];
  float* out = (float*)d_out;

  char* ws = (char*)d_ws;
  ushort* Xb  = (ushort*)(ws);                        // [4096,1024] bf16   8 MiB
  ushort* Wqt = (ushort*)(ws + (8ull << 20));         // [3072,1024] bf16   6 MiB
  ushort* Wot = (ushort*)(ws + (14ull << 20));        // [1024,1024] bf16   2 MiB
  ushort* Qv  = (ushort*)(ws + (16ull << 20));        // [B,H,T,Dh] bf16    8 MiB
  ushort* Kv  = (ushort*)(ws + (24ull << 20));        // [B,H,T,Dh] bf16    8 MiB
  ushort* Vt  = (ushort*)(ws + (32ull << 20));        // [B,H,Dh,T] bf16    8 MiB
  ushort* Yb  = Xb;  // alias: Xb is dead after the QKV GEMM

  // 1) cast x -> bf16
  cast4_kernel<<<(TB * TT * DM / 4 + 255) / 256, 256, 0, stream>>>(x, Xb, TB * TT * DM / 4);
  // 2) transpose-cast weights to B^T form
  transpose_cast_kernel<<<dim3(3 * DM / 32, DM / 32), dim3(32, 8), 0, stream>>>(w_qkv, Wqt, DM, 3 * DM);
  transpose_cast_kernel<<<dim3(DM / 32, DM / 32), dim3(32, 8), 0, stream>>>(w_out, Wot, DM, DM);
  // 3) QKV projection with split-heads scatter (Q pre-scaled; V transposed)
  gemm_bt_kernel<1><<<(TB * TT / 128) * (3 * DM / 128), 256, 0, stream>>>(
      Xb, Wqt, nullptr, Qv, Kv, Vt, TB * TT, 3 * DM, DM);
  // 4) fused causal attention -> Y [4096,1024] bf16
  attn_kernel<<<TB * NH * (TT / 128), 512, 0, stream>>>(Qv, Kv, Vt, Yb);
  // 5) output projection -> fp32 out
  gemm_bt_kernel<0><<<(TB * TT / 128) * (DM / 128), 256, 0, stream>>>(
      Yb, Wot, out, nullptr, nullptr, nullptr, TB * TT, DM, DM);
}

// Round 8
// 197.173 us; speedup vs baseline: 1.3076x; 1.0224x over previous
//
#include <hip/hip_runtime.h>
#include <stdint.h>

// Problem constants (from reference): B=2, T=2048, D_MODEL=1024, H=16, Dh=64
#define TB 2
#define TT 2048
#define DM 1024
#define NH 16
#define DH 64

typedef __bf16 bf16x8 __attribute__((ext_vector_type(8)));
typedef __bf16 bf16x2 __attribute__((ext_vector_type(2)));
typedef float f32x4 __attribute__((ext_vector_type(4)));

#define LOG2E 1.4426950408889634f
// Q pre-scale: fold 1/sqrt(Dh) and log2(e) so softmax runs in base-2 domain
#define QSCALE (0.125f * LOG2E)

__device__ __forceinline__ ushort f2bf(float f) {
  uint32_t u = __builtin_bit_cast(uint32_t, f);
  u += 0x7FFFu + ((u >> 16) & 1u);
  return (ushort)(u >> 16);
}

__device__ __forceinline__ uint32_t pk_bf16(float lo, float hi) {
  bf16x2 t;
  t[0] = (__bf16)lo;
  t[1] = (__bf16)hi;
  return __builtin_bit_cast(uint32_t, t);
}

__device__ __forceinline__ void gload_lds16(const void* g, void* l) {
  __builtin_amdgcn_global_load_lds(
      (__attribute__((address_space(1))) void*)g,
      (__attribute__((address_space(3))) void*)l, 16, 0, 0);
}

// ---------------- cast x fp32 -> bf16 (vectorized x4) ----------------
__global__ void cast4_kernel(const float* __restrict__ in, ushort* __restrict__ out, int n4) {
  int i = blockIdx.x * blockDim.x + threadIdx.x;
  if (i < n4) {
    float4 v = ((const float4*)in)[i];
    ushort4 o;
    o.x = f2bf(v.x); o.y = f2bf(v.y); o.z = f2bf(v.z); o.w = f2bf(v.w);
    ((ushort4*)out)[i] = o;
  }
}

// ---------------- transpose + cast: w[K][N] fp32 -> wt[N][K] bf16 ----------------
__global__ void transpose_cast_kernel(const float* __restrict__ w, ushort* __restrict__ wt,
                                      int K, int N) {
  __shared__ float tile[32][33];
  int n0 = blockIdx.x * 32, k0 = blockIdx.y * 32;
  int tx = threadIdx.x, ty = threadIdx.y;  // (32, 8)
#pragma unroll
  for (int i = 0; i < 4; ++i)
    tile[ty + i * 8][tx] = w[(size_t)(k0 + ty + i * 8) * N + n0 + tx];
  __syncthreads();
#pragma unroll
  for (int i = 0; i < 4; ++i)
    wt[(size_t)(n0 + ty + i * 8) * K + k0 + tx] = f2bf(tile[tx][ty + i * 8]);
}

// ---------------- GEMM: C = A[M,K] @ Bt[N,K]^T, bf16 in / fp32 accum ----------------
// 128x128 tile, BK=32, 4 waves each 64x64. Double-buffered LDS, single barrier per K-step.
// XCD-aware block swizzle (grid % 8 == 0 for all call sites).
// EPI 0: fp32 out [M,N].  EPI 1: QKV scatter (Q*QSCALE,K -> [b,h,t,d] bf16; V -> [b,h,d,t] bf16).
template <int EPI>
__launch_bounds__(256)
__global__ void gemm_bt_kernel(const ushort* __restrict__ A, const ushort* __restrict__ Bt,
                               float* __restrict__ outF, ushort* __restrict__ Qo,
                               ushort* __restrict__ Ko, ushort* __restrict__ Vto,
                               int M, int N, int K) {
  __shared__ ushort As[2 * 128 * 32];
  __shared__ ushort Bs[2 * 128 * 32];
  const int tid = threadIdx.x;
  const int lane = tid & 63;
  const int w = tid >> 6;
  const int nb = N >> 7;
  // XCD swizzle (T1): contiguous tile chunk per XCD for L2 A/B-panel reuse
  const int bid = blockIdx.x;
  const int bid2 = (bid & 7) * ((int)gridDim.x >> 3) + (bid >> 3);
  const int bx = bid2 % nb, by = bid2 / nb;
  const int m0 = by << 7, n0 = bx << 7;
  const int wr = (w >> 1) << 6, wc = (w & 1) << 6;
  const int g = lane >> 4, r16 = lane & 15;

  f32x4 acc[4][4] = {};

  const char* Ab = (const char*)A;
  const char* Bb = (const char*)Bt;
  char* AsB = (char*)As;
  char* BsB = (char*)Bs;

  auto stage = [&](int buf, int k0) {
#pragma unroll
    for (int i = 0; i < 2; ++i) {
      int o = (w << 11) + (i << 10) + (lane << 4);
      int row = o >> 6;
      int chl = ((o >> 4) & 3) ^ ((row >> 1) & 3);  // inverse-swizzled source chunk
      gload_lds16(Ab + (size_t)((m0 + row) * K + k0) * 2 + (chl << 4), AsB + (buf << 13) + o);
      gload_lds16(Bb + (size_t)((n0 + row) * K + k0) * 2 + (chl << 4), BsB + (buf << 13) + o);
    }
  };

  const int NK = K >> 5;
  stage(0, 0);
  for (int kt = 0; kt < NK; ++kt) {
    const int cur = kt & 1;
    __syncthreads();  // drains own staging of buf[cur]; prior reads of buf[cur^1] already done
    if (kt + 1 < NK) stage(cur ^ 1, (kt + 1) << 5);

    const char* Ac = AsB + (cur << 13);
    const char* Bc = BsB + (cur << 13);
    bf16x8 af[4], bfr[4];
#pragma unroll
    for (int m = 0; m < 4; ++m) {
      int rowA = wr + (m << 4) + r16;
      af[m] = *(const bf16x8*)(Ac + rowA * 64 + ((g ^ ((rowA >> 1) & 3)) << 4));
      int rowB = wc + (m << 4) + r16;
      bfr[m] = *(const bf16x8*)(Bc + rowB * 64 + ((g ^ ((rowB >> 1) & 3)) << 4));
    }
#pragma unroll
    for (int m = 0; m < 4; ++m)
#pragma unroll
      for (int n = 0; n < 4; ++n)
        acc[m][n] = __builtin_amdgcn_mfma_f32_16x16x32_bf16(af[m], bfr[n], acc[m][n], 0, 0, 0);
  }

  if (EPI == 0) {
#pragma unroll
    for (int m = 0; m < 4; ++m)
#pragma unroll
      for (int n = 0; n < 4; ++n)
#pragma unroll
        for (int r = 0; r < 4; ++r) {
          int row = m0 + wr + (m << 4) + (g << 2) + r;
          int col = n0 + wc + (n << 4) + r16;
          outF[(size_t)row * N + col] = acc[m][n][r];
        }
  } else {
    const int colBase = n0 + wc;
#pragma unroll
    for (int m = 0; m < 4; ++m) {
      int trow = m0 + wr + (m << 4) + (g << 2);  // t base for r=0 (b uniform per block)
      int b = trow >> 11;
      int tt = trow & (TT - 1);
#pragma unroll
      for (int n = 0; n < 4; ++n) {
        int e = colBase + (n << 4) + r16;
        int part = e >> 10;
        int rem = e & 1023;
        int h = rem >> 6, d = rem & 63;
        int bh = b * NH + h;
        if (part == 2) {
          ushort p0 = f2bf(acc[m][n][0]), p1 = f2bf(acc[m][n][1]);
          ushort p2 = f2bf(acc[m][n][2]), p3 = f2bf(acc[m][n][3]);
          uint2 pk;
          pk.x = (uint32_t)p0 | ((uint32_t)p1 << 16);
          pk.y = (uint32_t)p2 | ((uint32_t)p3 << 16);
          *(uint2*)(Vto + (size_t)(bh * DH + d) * TT + tt) = pk;
        } else {
          ushort* dstp = (part == 0) ? Qo : Ko;
          float sc = (part == 0) ? QSCALE : 1.0f;
#pragma unroll
          for (int r = 0; r < 4; ++r)
            dstp[(size_t)(bh * TT + tt + r) * DH + d] = f2bf(acc[m][n][r] * sc);
        }
      }
    }
  }
}

// ---------------- fused causal flash attention (v4: paired tiles, K/V dbuf) --------
// Grid: 256 blocks (8 pairs x 32 bh), 512 threads (8 waves) -> exactly 1 block/CU.
// Block processes q-tile p AND q-tile 15-p: uniform 17 chunks per block (no stragglers).
// KVBLK=128, K/V double-buffered (stage c+1 overlaps compute c, single barrier/chunk).
// Diagonal chunk: wave-uniform skip (QK m<=w, pack m<=(w|1), PV ks<=w>>1).
// S^T = K @ Q^T; defer-rescale THR=8; setprio around MFMA clusters.
__launch_bounds__(512)
__global__ void attn_kernel(const ushort* __restrict__ Qg, const ushort* __restrict__ Kg,
                            const ushort* __restrict__ Vtg, ushort* __restrict__ Y) {
  __shared__ ushort Ks[2 * 128 * 64];   // [buf][k][d] 16KB/buf, row 128B, swz ^(row&7)
  __shared__ ushort Vs[2 * 64 * 128];   // [buf][d][k] 16KB/buf, row 256B, swz ^(row&15)
  __shared__ ushort Ps[128 * 128];      // [q][k] row 256B, swz ^(row&15); rows wave-private
  const int tid = threadIdx.x;
  const int lane = tid & 63;
  const int w = tid >> 6;          // 0..7
  const int g = lane >> 4, r16 = lane & 15;
  const int bidx = blockIdx.x;
  const int p = bidx >> 5;         // pair index 0..7
  const int bh = bidx & 31;
  const int prow = (w << 4) + r16; // this lane's P row (q-local)

  const char* KgB = (const char*)Kg;
  const char* VtB = (const char*)Vtg;
  char* KsB = (char*)Ks;
  char* VsB = (char*)Vs;
  char* PsB = (char*)Ps;

  auto stage = [&](int c) {
    const int buf = c & 1;
    const int k0 = c << 7;
#pragma unroll
    for (int i = 0; i < 2; ++i) {
      int o = (tid << 4) + (i << 13);       // 512 thr x 2 x 16B = 16KB each
      int krow = o >> 7;
      int kchl = ((o >> 4) & 7) ^ (krow & 7);
      gload_lds16(KgB + (size_t)(bh * TT + k0 + krow) * 128 + (kchl << 4),
                  KsB + (buf << 14) + o);
      int vrow = o >> 8;
      int vchl = ((o >> 4) & 15) ^ (vrow & 15);
      gload_lds16(VtB + (size_t)(bh * DH + vrow) * 4096 + k0 * 2 + (vchl << 4),
                  VsB + (buf << 14) + o);
    }
  };

#pragma unroll 1
  for (int t = 0; t < 2; ++t) {
    const int qi = (t == 0) ? p : 15 - p;
    const int q0 = qi << 7;
    const int qw = q0 + (w << 4);    // wave's first q row

    // Q fragments (B-operand layout): q = qw + r16, d = dh*32 + g*8 .. +7
    bf16x8 qf[2];
#pragma unroll
    for (int dh = 0; dh < 2; ++dh)
      qf[dh] = *(const bf16x8*)(Qg + (size_t)(bh * TT + qw + r16) * DH + dh * 32 + g * 8);

    float mrun = -INFINITY;
    float lrun = 0.f;
    f32x4 oacc[4] = {};

    __syncthreads();   // all waves done reading previous pass's LDS
    stage(0);

    for (int c = 0; c <= qi; ++c) {
      __syncthreads();  // drains own stage(c); readers of buf[c^1] already finished
      if (c < qi) stage(c + 1);

      const int k0 = c << 7;
      const int kbuf = (c & 1) << 14;
      const bool diag = (c == qi);
      const int mQK = diag ? w : 7;          // QK m-tiles needed
      const int mPK = diag ? (w | 1) : 7;    // pack m-tiles (round up to ks-slot pair)
      const int ksL = diag ? (w >> 1) : 3;   // PV k-slots needed

      // S^T = K @ Q^T : sacc[m] reg r -> k = k0 + m*16 + g*4 + r, q = qw + r16
      f32x4 sacc[8] = {};
      __builtin_amdgcn_s_setprio(1);
#pragma unroll
      for (int dh = 0; dh < 2; ++dh) {
#pragma unroll
        for (int m = 0; m < 8; ++m) {
          if (m <= mQK) {
            int krow = (m << 4) + r16;
            bf16x8 kf = *(const bf16x8*)(KsB + kbuf + krow * 128 +
                                         ((((dh << 2) + g) ^ (krow & 7)) << 4));
            sacc[m] = __builtin_amdgcn_mfma_f32_16x16x32_bf16(kf, qf[dh], sacc[m], 0, 0, 0);
          }
        }
      }
      __builtin_amdgcn_s_setprio(0);

      float cm = -1e30f;
      if (diag) {  // per-element causal mask (covers fully-masked m in (w, w|1] too)
        const int qg = qw + r16;
#pragma unroll
        for (int m = 0; m < 8; ++m) {
          if (m <= mPK) {
#pragma unroll
            for (int r = 0; r < 4; ++r) {
              int kg = k0 + (m << 4) + (g << 2) + r;
              float s = sacc[m][r];
              s = (kg > qg) ? -1e30f : s;
              sacc[m][r] = s;
              cm = fmaxf(cm, s);
            }
          }
        }
      } else {
#pragma unroll
        for (int m = 0; m < 8; ++m)
#pragma unroll
          for (int r = 0; r < 4; ++r) cm = fmaxf(cm, sacc[m][r]);
      }
      cm = fmaxf(cm, __shfl_xor(cm, 16));
      cm = fmaxf(cm, __shfl_xor(cm, 32));

      // defer-rescale (T13): skip O-rescale while chunk max stays within 2^8 of running max
      if (!__all(cm <= mrun + 8.f)) {
        float mnew = fmaxf(mrun, cm);
        float fac = exp2f(mrun - mnew);
        lrun *= fac;
        mrun = mnew;
        float facO[4];
#pragma unroll
        for (int r = 0; r < 4; ++r) facO[r] = __shfl(fac, (g << 2) + r);
#pragma unroll
        for (int nd = 0; nd < 4; ++nd)
#pragma unroll
          for (int r = 0; r < 4; ++r) oacc[nd][r] *= facO[r];
      }

      // P = 2^(s - mrun), pack 4 consecutive k -> 8B LDS write
      float cs = 0.f;
#pragma unroll
      for (int m = 0; m < 8; ++m) {
        if (m <= mPK) {
          float p0 = exp2f(sacc[m][0] - mrun);
          float p1 = exp2f(sacc[m][1] - mrun);
          float p2 = exp2f(sacc[m][2] - mrun);
          float p3 = exp2f(sacc[m][3] - mrun);
          cs += (p0 + p1) + (p2 + p3);
          uint2 pk;
          pk.x = pk_bf16(p0, p1);
          pk.y = pk_bf16(p2, p3);
          int ch = ((m << 1) + (g >> 1)) ^ (prow & 15);
          *(uint2*)(PsB + prow * 256 + (ch << 4) + ((g & 1) << 3)) = pk;
        }
      }
      cs += __shfl_xor(cs, 16);
      cs += __shfl_xor(cs, 32);
      lrun += cs;

      // PV: oacc[nd] += P[q][k] * Vt[d][k]
      __builtin_amdgcn_s_setprio(1);
#pragma unroll
      for (int ks = 0; ks < 4; ++ks) {
        if (ks <= ksL) {
          bf16x8 pa = *(const bf16x8*)(PsB + prow * 256 + ((((ks << 2) + g) ^ (prow & 15)) << 4));
          bf16x8 vb[4];
#pragma unroll
          for (int nd = 0; nd < 4; ++nd) {
            int vrow = (nd << 4) + r16;
            vb[nd] = *(const bf16x8*)(VsB + kbuf + vrow * 256 +
                                      ((((ks << 2) + g) ^ (vrow & 15)) << 4));
          }
#pragma unroll
          for (int nd = 0; nd < 4; ++nd)
            oacc[nd] = __builtin_amdgcn_mfma_f32_16x16x32_bf16(pa, vb[nd], oacc[nd], 0, 0, 0);
        }
      }
      __builtin_amdgcn_s_setprio(0);
    }

    // normalize + store Y[b][t][h*64+d] bf16
    const int b = bh >> 4, h = bh & 15;
    float inv = 1.0f / lrun;
    float invO[4];
#pragma unroll
    for (int r = 0; r < 4; ++r) invO[r] = __shfl(inv, (g << 2) + r);
#pragma unroll
    for (int nd = 0; nd < 4; ++nd)
#pragma unroll
      for (int r = 0; r < 4; ++r) {
        int tq = q0 + (w << 4) + (g << 2) + r;
        int col = h * DH + (nd << 4) + r16;
        Y[(size_t)(b * TT + tq) * DM + col] = f2bf(oacc[nd][r] * invO[r]);
      }
  }
}

// ---------------- launch ----------------
extern "C" void kernel_launch(void* const* d_in, const int* in_sizes, int n_in,
                              void* d_out, int out_size, void* d_ws, size_t ws_size,
                              hipStream_t stream) {
  const float* x = (const float*)d_in[0];
  // d_in[1] = mask (int32 tril) -- causal structure is known, unused
  const float* w_qkv = (const float*)d_in[2];
  const float* w_out = (const float*)d_in[3];
  float* out = (float*)d_out;

  char* ws = (char*)d_ws;
  ushort* Xb  = (ushort*)(ws);                        // [4096,1024] bf16   8 MiB
  ushort* Wqt = (ushort*)(ws + (8ull << 20));         // [3072,1024] bf16   6 MiB
  ushort* Wot = (ushort*)(ws + (14ull << 20));        // [1024,1024] bf16   2 MiB
  ushort* Qv  = (ushort*)(ws + (16ull << 20));        // [B,H,T,Dh] bf16    8 MiB
  ushort* Kv  = (ushort*)(ws + (24ull << 20));        // [B,H,T,Dh] bf16    8 MiB
  ushort* Vt  = (ushort*)(ws + (32ull << 20));        // [B,H,Dh,T] bf16    8 MiB
  ushort* Yb  = Xb;  // alias: Xb is dead after the QKV GEMM

  // 1) cast x -> bf16
  cast4_kernel<<<(TB * TT * DM / 4 + 255) / 256, 256, 0, stream>>>(x, Xb, TB * TT * DM / 4);
  // 2) transpose-cast weights to B^T form
  transpose_cast_kernel<<<dim3(3 * DM / 32, DM / 32), dim3(32, 8), 0, stream>>>(w_qkv, Wqt, DM, 3 * DM);
  transpose_cast_kernel<<<dim3(DM / 32, DM / 32), dim3(32, 8), 0, stream>>>(w_out, Wot, DM, DM);
  // 3) QKV projection with split-heads scatter (Q pre-scaled; V transposed)
  gemm_bt_kernel<1><<<(TB * TT / 128) * (3 * DM / 128), 256, 0, stream>>>(
      Xb, Wqt, nullptr, Qv, Kv, Vt, TB * TT, 3 * DM, DM);
  // 4) fused causal attention -> Y [4096,1024] bf16 (256 blocks: 8 pairs x 32 bh)
  attn_kernel<<<8 * TB * NH, 512, 0, stream>>>(Qv, Kv, Vt, Yb);
  // 5) output projection -> fp32 out
  gemm_bt_kernel<0><<<(TB * TT / 128) * (DM / 128), 256, 0, stream>>>(
      Yb, Wot, out, nullptr, nullptr, nullptr, TB * TT, DM, DM);
}